// Round 3
// baseline (196.617 us; speedup 1.0000x reference)
//
#include <hip/hip_runtime.h>
#include <math.h>

#define HW 4096

// ws layout (floats):
//   Wt1   @ 0        : 192*576  = 110592   (Wt1[c*576+oc] = W1[oc*192+c])
//   Wtp   @ 110592   : 192*192  = 36864    (Wtp[c*192+oc] = Wp[oc*192+c])
//   W2t   @ 147456   : 9*576    = 5184     (W2t[tap*576+c] = W2[c*9+tap])
//   qkv1  @ 152640   : 2*18*4096*32 = 4718592   [b][g][pix][d], g=q3*6+head
//   attnO @ 4871232  : 2*192*4096   = 1572864   [b][c][pix] (d-major)

// ---------------------------------------------------------------------------
// K0: weight transposes so GEMM weight reads are wave-uniform (s_load) and
// depthwise weights are tap-major for LDS staging.
// ---------------------------------------------------------------------------
__global__ __launch_bounds__(256) void k_wt(const float* __restrict__ W1,
    const float* __restrict__ Wp, const float* __restrict__ W2,
    float* __restrict__ Wt1, float* __restrict__ Wtp, float* __restrict__ W2t)
{
    int idx = blockIdx.x * 256 + threadIdx.x;
    if (idx < 110592) {                     // Wt1
        int c = idx / 576, oc = idx - c * 576;
        Wt1[idx] = W1[oc * 192 + c];
    } else if (idx < 110592 + 36864) {      // Wtp
        int r = idx - 110592;
        int c = r / 192, oc = r - c * 192;
        Wtp[r] = Wp[oc * 192 + c];
    } else if (idx < 110592 + 36864 + 5184) { // W2t
        int r = idx - 147456;
        int tap = r / 576, c = r - tap * 576;
        W2t[r] = W2[c * 9 + tap];
    }
}

// ---------------------------------------------------------------------------
// K1: 1x1 QKV conv as scalar-broadcast GEMM.
// 128 thr/block, each thread owns 1 px x 16 oc. grid (64, 36):
//   pxg = bx*128+t (both batches folded), oc0 = by*16.
// Weights wave-uniform (s_load, 16 SGPR/iter -> prefetchable);
// x coalesced b32 global loads (L2-resident after first oc-group).
// out: [b][g][pix][32] d-contiguous.
// ---------------------------------------------------------------------------
__global__ __launch_bounds__(128) void k_qkv1(const float* __restrict__ x,
    const float* __restrict__ Wt1, const float* __restrict__ b1,
    float* __restrict__ out)
{
    const int t = threadIdx.x;
    const int pxg = blockIdx.x * 128 + t;
    const int b = pxg >> 12, px = pxg & 4095;
    const int oc0 = blockIdx.y * 16;
    const float* xb = x + ((size_t)b * 192 << 12) + px;
    const float4* wb = (const float4*)(Wt1 + oc0);      // row stride 144 float4
    const float4* bb = (const float4*)(b1 + oc0);
    float4 a0 = bb[0], a1 = bb[1], a2 = bb[2], a3 = bb[3];
    #pragma unroll 4
    for (int c = 0; c < 192; ++c) {
        float xv = xb[(size_t)c << 12];
        float4 w0 = wb[c * 144 + 0];
        float4 w1 = wb[c * 144 + 1];
        float4 w2 = wb[c * 144 + 2];
        float4 w3 = wb[c * 144 + 3];
        a0.x = fmaf(w0.x, xv, a0.x); a0.y = fmaf(w0.y, xv, a0.y);
        a0.z = fmaf(w0.z, xv, a0.z); a0.w = fmaf(w0.w, xv, a0.w);
        a1.x = fmaf(w1.x, xv, a1.x); a1.y = fmaf(w1.y, xv, a1.y);
        a1.z = fmaf(w1.z, xv, a1.z); a1.w = fmaf(w1.w, xv, a1.w);
        a2.x = fmaf(w2.x, xv, a2.x); a2.y = fmaf(w2.y, xv, a2.y);
        a2.z = fmaf(w2.z, xv, a2.z); a2.w = fmaf(w2.w, xv, a2.w);
        a3.x = fmaf(w3.x, xv, a3.x); a3.y = fmaf(w3.y, xv, a3.y);
        a3.z = fmaf(w3.z, xv, a3.z); a3.w = fmaf(w3.w, xv, a3.w);
    }
    const int g = oc0 >> 5, dd = oc0 & 31;
    float* ob = out + ((((size_t)(b * 18 + g) << 12) + px) << 5) + dd;
    *(float4*)(ob + 0) = a0;  *(float4*)(ob + 4) = a1;
    *(float4*)(ob + 8) = a2;  *(float4*)(ob + 12) = a3;
}

// ---------------------------------------------------------------------------
// K2: fused depthwise-3x3 + neighborhood attention.
// Block: 256 thr = (b, head, 8x8 px tile); 4 lanes per pixel (d-split).
// k AND v halos stored as packed bf16 in LDS (halves QK/PV DS traffic,
// 36.7 KB LDS -> 4 blocks/CU). rinv (k l2-norm) kept fp32, applied to logits.
// ---------------------------------------------------------------------------
__device__ inline unsigned bfpack2(float x, float y) {
    unsigned ux = __float_as_uint(x), uy = __float_as_uint(y);
    ux = (ux + 0x7fffu + ((ux >> 16) & 1u)) >> 16;
    uy = (uy + 0x7fffu + ((uy >> 16) & 1u)) & 0xffff0000u;
    return ux | uy;
}

__global__ __launch_bounds__(256) void k_attn(const float* __restrict__ qkv1,
    const float* __restrict__ W2t, const float* __restrict__ b2,
    const float* __restrict__ temp, const float* __restrict__ rpb,
    float* __restrict__ out)
{
    __shared__ __align__(16) unsigned ksu[196 * 20];    // bf16 k halo (packed)
    __shared__ __align__(16) unsigned vs[196 * 20];     // bf16 v halo (packed)
    __shared__ float rinvs[196];
    __shared__ float rpbs[169];
    __shared__ __align__(16) float wsm[3 * 288];        // [plane][tap][32ch]
    __shared__ __align__(16) float bsm[96];             // [plane][32ch]

    const int t = threadIdx.x;
    const int ti = blockIdx.x >> 3, tj = blockIdx.x & 7;
    const int head = blockIdx.y;
    const int b = blockIdx.z;
    const int i0 = ti * 8, j0 = tj * 8;
    const int r0 = min(max(i0 - 3, 0), 50);
    const int c0 = min(max(j0 - 3, 0), 50);

    // ---- cooperative stage of dw weights / bias / rpb ----
    for (int idx = t; idx < 864; idx += 256) {
        int pl = idx / 288, rem = idx - pl * 288;
        int tap = rem >> 5, ch = rem & 31;
        wsm[idx] = W2t[tap * 576 + pl * 192 + head * 32 + ch];
    }
    for (int idx = t; idx < 96; idx += 256) {
        int pl = idx >> 5, ch = idx & 31;
        bsm[idx] = b2[pl * 192 + head * 32 + ch];
    }
    for (int idx = t; idx < 169; idx += 256) rpbs[idx] = rpb[head * 169 + idx];
    __syncthreads();

    // ---- per-lane dw weights into registers (chunk d4 = t&7, 4 ch each) ----
    const int d4 = t & 7;
    const int prow = t >> 3;
    float4 wk4[9], wv4[9];
    #pragma unroll
    for (int tap = 0; tap < 9; ++tap) {
        wk4[tap] = *(const float4*)&wsm[288 + tap * 32 + d4 * 4];
        wv4[tap] = *(const float4*)&wsm[576 + tap * 32 + d4 * 4];
    }
    const float4 bk4 = *(const float4*)&bsm[32 + d4 * 4];
    const float4 bv4 = *(const float4*)&bsm[64 + d4 * 4];
    const float* kplane = qkv1 + ((size_t)(b * 18 + 6 + head) << 17);
    const float* vplane = qkv1 + ((size_t)(b * 18 + 12 + head) << 17);

    // ---- halo staging: dw-conv of k and v, 196 positions x 8 chunks ----
    #pragma unroll
    for (int ph = 0; ph < 7; ++ph) {
        int p = prow + ph * 32;
        bool act = p < 196;
        float4 sk = bk4, sv = bv4;
        if (act) {
            int r = (p * 2341) >> 15;      // p/14
            int cc = p - r * 14;
            int gi = r0 + r, gj = c0 + cc;
            #pragma unroll
            for (int di = -1; di <= 1; ++di) {
                int ii = gi + di;
                if (ii < 0 || ii > 63) continue;
                #pragma unroll
                for (int dj = -1; dj <= 1; ++dj) {
                    int jj = gj + dj;
                    if (jj < 0 || jj > 63) continue;
                    int tap = (di + 1) * 3 + dj + 1;
                    size_t off = ((size_t)((ii << 6) + jj) << 5) + d4 * 4;
                    float4 kx = *(const float4*)(kplane + off);
                    float4 vx = *(const float4*)(vplane + off);
                    sk.x = fmaf(kx.x, wk4[tap].x, sk.x);
                    sk.y = fmaf(kx.y, wk4[tap].y, sk.y);
                    sk.z = fmaf(kx.z, wk4[tap].z, sk.z);
                    sk.w = fmaf(kx.w, wk4[tap].w, sk.w);
                    sv.x = fmaf(vx.x, wv4[tap].x, sv.x);
                    sv.y = fmaf(vx.y, wv4[tap].y, sv.y);
                    sv.z = fmaf(vx.z, wv4[tap].z, sv.z);
                    sv.w = fmaf(vx.w, wv4[tap].w, sv.w);
                }
            }
            uint2 pk;
            pk.x = bfpack2(sk.x, sk.y);
            pk.y = bfpack2(sk.z, sk.w);
            *(uint2*)&ksu[p * 20 + d4 * 2] = pk;
            uint2 pv;
            pv.x = bfpack2(sv.x, sv.y);
            pv.y = bfpack2(sv.z, sv.w);
            *(uint2*)&vs[p * 20 + d4 * 2] = pv;
        }
        float ss = act ? (sk.x*sk.x + sk.y*sk.y + sk.z*sk.z + sk.w*sk.w) : 0.f;
        ss += __shfl_xor(ss, 1);
        ss += __shfl_xor(ss, 2);
        ss += __shfl_xor(ss, 4);
        if (act && d4 == 0) rinvs[p] = 1.0f / fmaxf(sqrtf(ss), 1e-12f);
    }

    // ---- own q: dw-conv into registers (lane owns 8 ch: dsub*8..) ----
    const int pixel = t >> 2, dsub = t & 3;
    const int li = pixel >> 3, lj = pixel & 7;
    const int i = i0 + li, j = j0 + lj;
    const float* qplane = qkv1 + ((size_t)(b * 18 + head) << 17);
    float4 qa = *(const float4*)&bsm[dsub * 8];
    float4 qb = *(const float4*)&bsm[dsub * 8 + 4];
    #pragma unroll
    for (int di = -1; di <= 1; ++di) {
        int ii = i + di;
        if (ii < 0 || ii > 63) continue;
        #pragma unroll
        for (int dj = -1; dj <= 1; ++dj) {
            int jj = j + dj;
            if (jj < 0 || jj > 63) continue;
            int tap = (di + 1) * 3 + dj + 1;
            size_t off = ((size_t)((ii << 6) + jj) << 5) + dsub * 8;
            float4 xa = *(const float4*)(qplane + off);
            float4 xb = *(const float4*)(qplane + off + 4);
            float4 wa = *(const float4*)&wsm[tap * 32 + dsub * 8];
            float4 wb = *(const float4*)&wsm[tap * 32 + dsub * 8 + 4];
            qa.x = fmaf(xa.x, wa.x, qa.x); qa.y = fmaf(xa.y, wa.y, qa.y);
            qa.z = fmaf(xa.z, wa.z, qa.z); qa.w = fmaf(xa.w, wa.w, qa.w);
            qb.x = fmaf(xb.x, wb.x, qb.x); qb.y = fmaf(xb.y, wb.y, qb.y);
            qb.z = fmaf(xb.z, wb.z, qb.z); qb.w = fmaf(xb.w, wb.w, qb.w);
        }
    }
    float qs = qa.x*qa.x + qa.y*qa.y + qa.z*qa.z + qa.w*qa.w
             + qb.x*qb.x + qb.y*qb.y + qb.z*qb.z + qb.w*qb.w;
    qs += __shfl_xor(qs, 1);
    qs += __shfl_xor(qs, 2);
    float qinv = 1.0f / fmaxf(sqrtf(qs), 1e-12f);
    qa.x *= qinv; qa.y *= qinv; qa.z *= qinv; qa.w *= qinv;
    qb.x *= qinv; qb.y *= qinv; qb.z *= qinv; qb.w *= qinv;
    __syncthreads();

    // ---- QK^T + bias + temperature (k from bf16 LDS) ----
    const int si = min(max(i - 3, 0), 57), sj = min(max(j - 3, 0), 57);
    const int pr0 = si - r0, pc0 = sj - c0;
    const float th = temp[head];
    const int bi0 = (si - i + 6) * 13 + (sj - j + 6);
    const int nbase = pr0 * 14 + pc0;
    float a[49];
    #pragma unroll
    for (int ki = 0; ki < 7; ++ki) {
        #pragma unroll
        for (int kj = 0; kj < 7; ++kj) {
            int nb = nbase + ki * 14 + kj;
            uint4 uk = *(const uint4*)&ksu[nb * 20 + dsub * 4];
            float dot = qa.x * __uint_as_float(uk.x << 16);
            dot = fmaf(qa.y, __uint_as_float(uk.x & 0xffff0000u), dot);
            dot = fmaf(qa.z, __uint_as_float(uk.y << 16),         dot);
            dot = fmaf(qa.w, __uint_as_float(uk.y & 0xffff0000u), dot);
            dot = fmaf(qb.x, __uint_as_float(uk.z << 16),         dot);
            dot = fmaf(qb.y, __uint_as_float(uk.z & 0xffff0000u), dot);
            dot = fmaf(qb.z, __uint_as_float(uk.w << 16),         dot);
            dot = fmaf(qb.w, __uint_as_float(uk.w & 0xffff0000u), dot);
            dot += __shfl_xor(dot, 1);
            dot += __shfl_xor(dot, 2);
            a[ki * 7 + kj] = fmaf(dot, rinvs[nb], rpbs[bi0 + ki * 13 + kj]) * th;
        }
    }

    // ---- softmax (redundant x4 lanes) ----
    float m = a[0];
    #pragma unroll
    for (int kk = 1; kk < 49; ++kk) m = fmaxf(m, a[kk]);
    float ssum = 0.f;
    #pragma unroll
    for (int kk = 0; kk < 49; ++kk) { a[kk] = __expf(a[kk] - m); ssum += a[kk]; }
    const float rs = 1.0f / ssum;

    // ---- PV from bf16 LDS ----
    float o[8];
    #pragma unroll
    for (int d = 0; d < 8; ++d) o[d] = 0.f;
    #pragma unroll
    for (int ki = 0; ki < 7; ++ki) {
        #pragma unroll
        for (int kj = 0; kj < 7; ++kj) {
            int nb = nbase + ki * 14 + kj;
            uint4 uv = *(const uint4*)&vs[nb * 20 + dsub * 4];
            float w = a[ki * 7 + kj];
            o[0] = fmaf(w, __uint_as_float(uv.x << 16),        o[0]);
            o[1] = fmaf(w, __uint_as_float(uv.x & 0xffff0000u), o[1]);
            o[2] = fmaf(w, __uint_as_float(uv.y << 16),        o[2]);
            o[3] = fmaf(w, __uint_as_float(uv.y & 0xffff0000u), o[3]);
            o[4] = fmaf(w, __uint_as_float(uv.z << 16),        o[4]);
            o[5] = fmaf(w, __uint_as_float(uv.z & 0xffff0000u), o[5]);
            o[6] = fmaf(w, __uint_as_float(uv.w << 16),        o[6]);
            o[7] = fmaf(w, __uint_as_float(uv.w & 0xffff0000u), o[7]);
        }
    }
    float* ob = out + ((size_t)(b * 192 + head * 32 + dsub * 8) << 12) + (i << 6) + j;
    #pragma unroll
    for (int dd = 0; dd < 8; ++dd) ob[(size_t)dd << 12] = o[dd] * rs;
}

// ---------------------------------------------------------------------------
// K3: 1x1 output projection, scalar-broadcast GEMM.
// 128 thr/block, 1 px x 16 oc per thread. grid (64, 12).
// in: [b][c][pix]; out NCHW [b][oc][pix] (both px-coalesced).
// ---------------------------------------------------------------------------
__global__ __launch_bounds__(128) void k_proj(const float* __restrict__ in,
    const float* __restrict__ Wtp, const float* __restrict__ bp,
    float* __restrict__ out)
{
    const int t = threadIdx.x;
    const int pxg = blockIdx.x * 128 + t;
    const int b = pxg >> 12, px = pxg & 4095;
    const int oc0 = blockIdx.y * 16;
    const float* ib = in + ((size_t)b * 192 << 12) + px;
    const float4* wb = (const float4*)(Wtp + oc0);      // row stride 48 float4
    const float4* bb = (const float4*)(bp + oc0);
    float4 a0 = bb[0], a1 = bb[1], a2 = bb[2], a3 = bb[3];
    #pragma unroll 4
    for (int c = 0; c < 192; ++c) {
        float xv = ib[(size_t)c << 12];
        float4 w0 = wb[c * 48 + 0];
        float4 w1 = wb[c * 48 + 1];
        float4 w2 = wb[c * 48 + 2];
        float4 w3 = wb[c * 48 + 3];
        a0.x = fmaf(w0.x, xv, a0.x); a0.y = fmaf(w0.y, xv, a0.y);
        a0.z = fmaf(w0.z, xv, a0.z); a0.w = fmaf(w0.w, xv, a0.w);
        a1.x = fmaf(w1.x, xv, a1.x); a1.y = fmaf(w1.y, xv, a1.y);
        a1.z = fmaf(w1.z, xv, a1.z); a1.w = fmaf(w1.w, xv, a1.w);
        a2.x = fmaf(w2.x, xv, a2.x); a2.y = fmaf(w2.y, xv, a2.y);
        a2.z = fmaf(w2.z, xv, a2.z); a2.w = fmaf(w2.w, xv, a2.w);
        a3.x = fmaf(w3.x, xv, a3.x); a3.y = fmaf(w3.y, xv, a3.y);
        a3.z = fmaf(w3.z, xv, a3.z); a3.w = fmaf(w3.w, xv, a3.w);
    }
    float* ob = out + (((size_t)b * 192 + oc0) << 12) + px;
    float av[16] = {a0.x,a0.y,a0.z,a0.w, a1.x,a1.y,a1.z,a1.w,
                    a2.x,a2.y,a2.z,a2.w, a3.x,a3.y,a3.z,a3.w};
    #pragma unroll
    for (int k = 0; k < 16; ++k) ob[(size_t)k << 12] = av[k];
}

extern "C" void kernel_launch(void* const* d_in, const int* in_sizes, int n_in,
                              void* d_out, int out_size, void* d_ws, size_t ws_size,
                              hipStream_t stream) {
    const float* x    = (const float*)d_in[0];
    const float* W1   = (const float*)d_in[1];
    const float* b1   = (const float*)d_in[2];
    const float* W2   = (const float*)d_in[3];
    const float* b2   = (const float*)d_in[4];
    const float* temp = (const float*)d_in[5];
    const float* rpb  = (const float*)d_in[6];
    const float* Wp   = (const float*)d_in[7];
    const float* bp   = (const float*)d_in[8];
    float* out = (float*)d_out;

    float* ws    = (float*)d_ws;
    float* Wt1   = ws;
    float* Wtp   = ws + 110592;
    float* W2t   = ws + 147456;
    float* qkv1  = ws + 152640;
    float* attnO = ws + 4871232;

    k_wt  <<<dim3(597), 256, 0, stream>>>(W1, Wp, W2, Wt1, Wtp, W2t);
    k_qkv1<<<dim3(64, 36), 128, 0, stream>>>(x, Wt1, b1, qkv1);
    k_attn<<<dim3(64, 6, 2), 256, 0, stream>>>(qkv1, W2t, b2, temp, rpb, attnO);
    k_proj<<<dim3(64, 12), 128, 0, stream>>>(attnO, Wtp, bp, out);
}

// Round 4
// 117.182 us; speedup vs baseline: 1.6779x; 1.6779x over previous
//
#include <hip/hip_runtime.h>
#include <math.h>

#define HW 4096

typedef __attribute__((ext_vector_type(8))) short short8;
typedef __attribute__((ext_vector_type(4))) float floatx4;

// ---- bf16 helpers (round-to-nearest-even) ----
__device__ inline float bflo(unsigned u) { return __uint_as_float(u << 16); }
__device__ inline float bfhi(unsigned u) { return __uint_as_float(u & 0xffff0000u); }
__device__ inline unsigned short f2bf(float x) {
    unsigned u = __float_as_uint(x);
    return (unsigned short)((u + 0x7fffu + ((u >> 16) & 1u)) >> 16);
}
__device__ inline unsigned f2bf2(float lo, float hi) {
    unsigned a = __float_as_uint(lo), b = __float_as_uint(hi);
    a = (a + 0x7fffu + ((a >> 16) & 1u)) >> 16;
    b = (b + 0x7fffu + ((b >> 16) & 1u)) & 0xffff0000u;
    return a | b;
}
// quad (lanes 4k..4k+3) sum via DPP quad_perm — VALU pipe, no DS traffic
__device__ inline float qred(float x) {
    x += __int_as_float(__builtin_amdgcn_update_dpp(0, __float_as_int(x), 0xB1, 0xF, 0xF, true));
    x += __int_as_float(__builtin_amdgcn_update_dpp(0, __float_as_int(x), 0x4E, 0xF, 0xF, true));
    return x;
}

// ws layout (bytes):
//   Wb1   @ 0        : 576*192*2   = 221184   bf16 [oc][c]
//   Wbp   @ 221184   : 192*192*2   = 73728    bf16 [oc][c]
//   xT    @ 294912   : 2*4096*192*2 = 3145728 bf16 [b*px][c]
//   qkv1b @ 3440640  : 2*18*4096*32*2 = 9437184  bf16 [b][g][px][32]
//   qkv2b @ 12877824 : 9437184                  (after depthwise)
//   attnO @ 22315008 : 2*4096*192*2 = 3145728 bf16 [b*px][c]

// ---------------------------------------------------------------------------
// K0: convert W1 / Wp to bf16 (already [oc][c] = MFMA B layout, no transpose).
// ---------------------------------------------------------------------------
__global__ __launch_bounds__(256) void k_cvt(const float* __restrict__ W1,
    const float* __restrict__ Wp, unsigned short* __restrict__ Wb1,
    unsigned short* __restrict__ Wbp)
{
    int idx = blockIdx.x * 256 + threadIdx.x;
    if (idx < 110592) Wb1[idx] = f2bf(W1[idx]);
    else if (idx < 147456) Wbp[idx - 110592] = f2bf(Wp[idx - 110592]);
}

// ---------------------------------------------------------------------------
// K1: transpose+convert x: fp32 [b][c][px] -> bf16 [b*px][c]  (GEMM A layout)
// ---------------------------------------------------------------------------
__global__ __launch_bounds__(256) void k_xt(const float* __restrict__ x,
    unsigned short* __restrict__ xT)
{
    __shared__ __align__(16) unsigned short tsm[64 * 196];
    const int t = threadIdx.x;
    const int px0 = blockIdx.x << 6;
    const int b = blockIdx.y;
    const float* xb = x + ((size_t)b * 192 << 12);
    #pragma unroll
    for (int pass = 0; pass < 12; ++pass) {
        int c = pass * 16 + (t >> 4);
        int p4 = t & 15;
        float4 v = *(const float4*)&xb[((size_t)c << 12) + px0 + p4 * 4];
        tsm[(p4 * 4 + 0) * 196 + c] = f2bf(v.x);
        tsm[(p4 * 4 + 1) * 196 + c] = f2bf(v.y);
        tsm[(p4 * 4 + 2) * 196 + c] = f2bf(v.z);
        tsm[(p4 * 4 + 3) * 196 + c] = f2bf(v.w);
    }
    __syncthreads();
    #pragma unroll
    for (int pass = 0; pass < 6; ++pass) {
        int idx = pass * 256 + t;
        int m = idx / 24, c8 = idx % 24;
        uint2 lo = *(const uint2*)&tsm[m * 196 + c8 * 8];
        uint2 hi = *(const uint2*)&tsm[m * 196 + c8 * 8 + 4];
        uint4 o = make_uint4(lo.x, lo.y, hi.x, hi.y);
        *(uint4*)&xT[((size_t)(b << 12) + px0 + m) * 192 + c8 * 8] = o;
    }
}

// ---------------------------------------------------------------------------
// K2: QKV 1x1 conv as bf16 MFMA GEMM. M=8192(px) N=576(oc) K=192.
// Block 256thr/4 waves: tile 64m x 64n; wave w owns n=w*16..+15, all 64 m.
// A/B rows in LDS stride 200 bf16 -> frag b128 reads quad-group (m+kq)%8.
// out bf16 [b][g][px][32], bias fused in epilogue.
// ---------------------------------------------------------------------------
__global__ __launch_bounds__(256) void k_gq(const unsigned short* __restrict__ xT,
    const unsigned short* __restrict__ Wb1, const float* __restrict__ b1,
    unsigned short* __restrict__ qkv)
{
    __shared__ __align__(16) unsigned short As[64 * 200];
    __shared__ __align__(16) unsigned short Bs[64 * 200];
    const int t = threadIdx.x;
    const int m0 = blockIdx.x * 64;
    const int n0 = blockIdx.y * 64;
    #pragma unroll
    for (int pass = 0; pass < 6; ++pass) {
        int idx = pass * 256 + t;
        int m = idx / 24, c16 = idx % 24;
        *(uint4*)&As[m * 200 + c16 * 8] = *(const uint4*)&xT[(size_t)(m0 + m) * 192 + c16 * 8];
        *(uint4*)&Bs[m * 200 + c16 * 8] = *(const uint4*)&Wb1[(size_t)(n0 + m) * 192 + c16 * 8];
    }
    __syncthreads();
    const int w = t >> 6, lane = t & 63;
    const int lm = lane & 15, lq = lane >> 4;
    floatx4 acc[4] = {};
    #pragma unroll
    for (int ks = 0; ks < 6; ++ks) {
        short8 bf = *(const short8*)&Bs[(w * 16 + lm) * 200 + ks * 32 + lq * 8];
        #pragma unroll
        for (int mt = 0; mt < 4; ++mt) {
            short8 af = *(const short8*)&As[(mt * 16 + lm) * 200 + ks * 32 + lq * 8];
            acc[mt] = __builtin_amdgcn_mfma_f32_16x16x32_bf16(af, bf, acc[mt], 0, 0, 0);
        }
    }
    __syncthreads();
    const float bias = b1[n0 + w * 16 + lm];
    #pragma unroll
    for (int mt = 0; mt < 4; ++mt)
        #pragma unroll
        for (int r = 0; r < 4; ++r)
            As[(mt * 16 + lq * 4 + r) * 72 + w * 16 + lm] = f2bf(acc[mt][r] + bias);
    __syncthreads();
    #pragma unroll
    for (int pass = 0; pass < 2; ++pass) {
        int idx = pass * 256 + t;           // 64 m x 8 n-groups
        int m = idx >> 3, n8 = idx & 7;
        uint4 val = *(const uint4*)&As[m * 72 + n8 * 8];
        int mg = m0 + m;
        int b = mg >> 12, px = mg & 4095;
        int oc = n0 + n8 * 8;
        int g = oc >> 5, d = oc & 31;
        *(uint4*)&qkv[((((size_t)(b * 18 + g) << 12) + px) << 5) + d] = val;
    }
}

// ---------------------------------------------------------------------------
// K3: depthwise 3x3, bf16 in/out, fp32 math, weights staged in LDS.
// Block: 64 px x 4 d8-chunks; grid (64 px-blocks, 36 bg).
// ---------------------------------------------------------------------------
__global__ __launch_bounds__(256) void k_dw(const unsigned short* __restrict__ in,
    const float* __restrict__ W2, const float* __restrict__ b2,
    unsigned short* __restrict__ outq)
{
    __shared__ float wsm[288];
    __shared__ float bsm[32];
    const int t = threadIdx.x;
    const int bg = blockIdx.y;
    const int g = (bg >= 18) ? bg - 18 : bg;
    const int cbase = (g / 6) * 192 + (g % 6) * 32;
    for (int idx = t; idx < 288; idx += 256)
        wsm[idx] = W2[(cbase + (idx & 31)) * 9 + (idx >> 5)];
    if (t < 32) bsm[t] = b2[cbase + t];
    __syncthreads();
    const int px = (blockIdx.x << 6) + (t >> 2);
    const int d8 = t & 3;
    const int i = px >> 6, j = px & 63;
    const unsigned short* base = in + ((size_t)bg << 17);
    float acc[8];
    #pragma unroll
    for (int e = 0; e < 8; ++e) acc[e] = bsm[d8 * 8 + e];
    #pragma unroll
    for (int di = -1; di <= 1; ++di) {
        int ii = i + di;
        if (ii < 0 || ii > 63) continue;
        #pragma unroll
        for (int dj = -1; dj <= 1; ++dj) {
            int jj = j + dj;
            if (jj < 0 || jj > 63) continue;
            int tap = (di + 1) * 3 + dj + 1;
            uint4 u = *(const uint4*)(base + ((((ii << 6) + jj) << 5) + d8 * 8));
            const float* wt = &wsm[tap * 32 + d8 * 8];
            acc[0] = fmaf(bflo(u.x), wt[0], acc[0]);
            acc[1] = fmaf(bfhi(u.x), wt[1], acc[1]);
            acc[2] = fmaf(bflo(u.y), wt[2], acc[2]);
            acc[3] = fmaf(bfhi(u.y), wt[3], acc[3]);
            acc[4] = fmaf(bflo(u.z), wt[4], acc[4]);
            acc[5] = fmaf(bfhi(u.z), wt[5], acc[5]);
            acc[6] = fmaf(bflo(u.w), wt[6], acc[6]);
            acc[7] = fmaf(bfhi(u.w), wt[7], acc[7]);
        }
    }
    uint4 o;
    o.x = f2bf2(acc[0], acc[1]); o.y = f2bf2(acc[2], acc[3]);
    o.z = f2bf2(acc[4], acc[5]); o.w = f2bf2(acc[6], acc[7]);
    *(uint4*)(outq + ((size_t)bg << 17) + ((size_t)px << 5) + d8 * 8) = o;
}

// ---------------------------------------------------------------------------
// K4: neighborhood attention. Block 256 = (b, head, 8x8 tile), 4 lanes/px.
// Staging: 196 lanes each fully own one halo pos: copy v, l2-normalize k
// (rinv folded into stored k-hat). kv[p][0..15]=k-hat,[16..31]=v (uints),
// stride 36 -> quad-group (p+d)%8, <=2-way conflicts. DPP quad reduces.
// out: attnO bf16 [b*px][c] (= proj GEMM A layout).
// ---------------------------------------------------------------------------
__global__ __launch_bounds__(256) void k_attn(const unsigned short* __restrict__ qkv,
    const float* __restrict__ temp, const float* __restrict__ rpb,
    unsigned short* __restrict__ attnO)
{
    __shared__ __align__(16) unsigned kv[196 * 36];
    __shared__ float rpbs[169];
    const int t = threadIdx.x;
    const int ti = blockIdx.x >> 3, tj = blockIdx.x & 7;
    const int head = blockIdx.y, b = blockIdx.z;
    const int i0 = ti * 8, j0 = tj * 8;
    const int r0 = min(max(i0 - 3, 0), 50), c0 = min(max(j0 - 3, 0), 50);
    const unsigned short* kpl = qkv + ((size_t)(b * 18 + 6 + head) << 17);
    const unsigned short* vpl = qkv + ((size_t)(b * 18 + 12 + head) << 17);

    if (t < 196) {
        int r = (t * 2341) >> 15, cc = t - r * 14;          // t/14, t%14
        int pix = ((r0 + r) << 6) + (c0 + cc);
        const unsigned* kg = (const unsigned*)(kpl + (pix << 5));
        const unsigned* vg = (const unsigned*)(vpl + (pix << 5));
        uint4 ku[4];
        float kf[32];
        float ss = 0.f;
        #pragma unroll
        for (int q = 0; q < 4; ++q) {
            ku[q] = *(const uint4*)(kg + q * 4);
            unsigned uu[4] = {ku[q].x, ku[q].y, ku[q].z, ku[q].w};
            #pragma unroll
            for (int e = 0; e < 4; ++e) {
                float lo = bflo(uu[e]), hi = bfhi(uu[e]);
                kf[q * 8 + e * 2] = lo; kf[q * 8 + e * 2 + 1] = hi;
                ss = fmaf(lo, lo, fmaf(hi, hi, ss));
            }
        }
        float rinv = 1.0f / fmaxf(sqrtf(ss), 1e-12f);
        #pragma unroll
        for (int q = 0; q < 4; ++q) {
            uint4 p;
            p.x = f2bf2(kf[q * 8 + 0] * rinv, kf[q * 8 + 1] * rinv);
            p.y = f2bf2(kf[q * 8 + 2] * rinv, kf[q * 8 + 3] * rinv);
            p.z = f2bf2(kf[q * 8 + 4] * rinv, kf[q * 8 + 5] * rinv);
            p.w = f2bf2(kf[q * 8 + 6] * rinv, kf[q * 8 + 7] * rinv);
            *(uint4*)&kv[t * 36 + q * 4] = p;
        }
        #pragma unroll
        for (int q = 0; q < 4; ++q)
            *(uint4*)&kv[t * 36 + 16 + q * 4] = *(const uint4*)(vg + q * 4);
    }
    if (t < 169) rpbs[t] = rpb[head * 169 + t];

    // own q: 8 channels per lane, quad-normalized
    const int px = t >> 2, dsub = t & 3;
    const int li = px >> 3, lj = px & 7;
    const int i = i0 + li, j = j0 + lj;
    const unsigned short* qpl = qkv + ((size_t)(b * 18 + head) << 17);
    uint4 qu = *(const uint4*)(qpl + ((((i << 6) + j) << 5) + dsub * 8));
    float qf[8];
    qf[0] = bflo(qu.x); qf[1] = bfhi(qu.x);
    qf[2] = bflo(qu.y); qf[3] = bfhi(qu.y);
    qf[4] = bflo(qu.z); qf[5] = bfhi(qu.z);
    qf[6] = bflo(qu.w); qf[7] = bfhi(qu.w);
    float qs = 0.f;
    #pragma unroll
    for (int e = 0; e < 8; ++e) qs = fmaf(qf[e], qf[e], qs);
    qs = qred(qs);
    float qinv = 1.0f / fmaxf(sqrtf(qs), 1e-12f);
    #pragma unroll
    for (int e = 0; e < 8; ++e) qf[e] *= qinv;
    __syncthreads();

    // QK^T + bias, scaled by temperature
    const int si = min(max(i - 3, 0), 57), sj = min(max(j - 3, 0), 57);
    const int pr0 = si - r0, pc0 = sj - c0;
    const float th = temp[head];
    const int bi0 = (si - i + 6) * 13 + (sj - j + 6);
    const int nbase = pr0 * 14 + pc0;
    float a[49];
    #pragma unroll
    for (int ki = 0; ki < 7; ++ki) {
        #pragma unroll
        for (int kj = 0; kj < 7; ++kj) {
            int nb = nbase + ki * 14 + kj;
            uint4 uk = *(const uint4*)&kv[nb * 36 + dsub * 4];
            float dot;
            dot = qf[0] * bflo(uk.x);
            dot = fmaf(qf[1], bfhi(uk.x), dot);
            dot = fmaf(qf[2], bflo(uk.y), dot);
            dot = fmaf(qf[3], bfhi(uk.y), dot);
            dot = fmaf(qf[4], bflo(uk.z), dot);
            dot = fmaf(qf[5], bfhi(uk.z), dot);
            dot = fmaf(qf[6], bflo(uk.w), dot);
            dot = fmaf(qf[7], bfhi(uk.w), dot);
            dot = qred(dot);
            a[ki * 7 + kj] = (dot + rpbs[bi0 + ki * 13 + kj]) * th;
        }
    }

    // softmax (replicated across the 4 lanes — bitwise identical)
    float m = a[0];
    #pragma unroll
    for (int kk = 1; kk < 49; ++kk) m = fmaxf(m, a[kk]);
    float ssum = 0.f;
    #pragma unroll
    for (int kk = 0; kk < 49; ++kk) { a[kk] = __expf(a[kk] - m); ssum += a[kk]; }
    const float rs = 1.0f / ssum;

    // PV
    float o[8];
    #pragma unroll
    for (int e = 0; e < 8; ++e) o[e] = 0.f;
    #pragma unroll
    for (int ki = 0; ki < 7; ++ki) {
        #pragma unroll
        for (int kj = 0; kj < 7; ++kj) {
            int nb = nbase + ki * 14 + kj;
            uint4 uv = *(const uint4*)&kv[nb * 36 + 16 + dsub * 4];
            float wgt = a[ki * 7 + kj];
            o[0] = fmaf(wgt, bflo(uv.x), o[0]);
            o[1] = fmaf(wgt, bfhi(uv.x), o[1]);
            o[2] = fmaf(wgt, bflo(uv.y), o[2]);
            o[3] = fmaf(wgt, bfhi(uv.y), o[3]);
            o[4] = fmaf(wgt, bflo(uv.z), o[4]);
            o[5] = fmaf(wgt, bfhi(uv.z), o[5]);
            o[6] = fmaf(wgt, bflo(uv.w), o[6]);
            o[7] = fmaf(wgt, bfhi(uv.w), o[7]);
        }
    }
    uint4 ov;
    ov.x = f2bf2(o[0] * rs, o[1] * rs);
    ov.y = f2bf2(o[2] * rs, o[3] * rs);
    ov.z = f2bf2(o[4] * rs, o[5] * rs);
    ov.w = f2bf2(o[6] * rs, o[7] * rs);
    *(uint4*)&attnO[((size_t)((b << 12) + (i << 6) + j)) * 192 + head * 32 + dsub * 8] = ov;
}

// ---------------------------------------------------------------------------
// K5: proj 1x1 as bf16 MFMA GEMM. M=8192 N=192 K=192. fp32 NCHW out + bias.
// ---------------------------------------------------------------------------
__global__ __launch_bounds__(256) void k_gp(const unsigned short* __restrict__ Ain,
    const unsigned short* __restrict__ Wbp, const float* __restrict__ bp,
    float* __restrict__ out)
{
    __shared__ __align__(16) unsigned short As[64 * 200];
    __shared__ __align__(16) unsigned short Bs[64 * 200];
    const int t = threadIdx.x;
    const int m0 = blockIdx.x * 64;
    const int n0 = blockIdx.y * 64;
    #pragma unroll
    for (int pass = 0; pass < 6; ++pass) {
        int idx = pass * 256 + t;
        int m = idx / 24, c16 = idx % 24;
        *(uint4*)&As[m * 200 + c16 * 8] = *(const uint4*)&Ain[(size_t)(m0 + m) * 192 + c16 * 8];
        *(uint4*)&Bs[m * 200 + c16 * 8] = *(const uint4*)&Wbp[(size_t)(n0 + m) * 192 + c16 * 8];
    }
    __syncthreads();
    const int w = t >> 6, lane = t & 63;
    const int lm = lane & 15, lq = lane >> 4;
    floatx4 acc[4] = {};
    #pragma unroll
    for (int ks = 0; ks < 6; ++ks) {
        short8 bf = *(const short8*)&Bs[(w * 16 + lm) * 200 + ks * 32 + lq * 8];
        #pragma unroll
        for (int mt = 0; mt < 4; ++mt) {
            short8 af = *(const short8*)&As[(mt * 16 + lm) * 200 + ks * 32 + lq * 8];
            acc[mt] = __builtin_amdgcn_mfma_f32_16x16x32_bf16(af, bf, acc[mt], 0, 0, 0);
        }
    }
    __syncthreads();
    float* fs = (float*)As;                 // [n][m] stride 68
    const float bias = bp[n0 + w * 16 + lm];
    #pragma unroll
    for (int mt = 0; mt < 4; ++mt)
        #pragma unroll
        for (int r = 0; r < 4; ++r)
            fs[(w * 16 + lm) * 68 + mt * 16 + lq * 4 + r] = acc[mt][r] + bias;
    __syncthreads();
    const int b = m0 >> 12, px0 = m0 & 4095;
    #pragma unroll
    for (int pass = 0; pass < 4; ++pass) {
        int idx = pass * 256 + t;           // 64 n x 16 m-quads
        int n = idx >> 4, m4 = idx & 15;
        float4 val = *(const float4*)&fs[n * 68 + m4 * 4];
        *(float4*)&out[((size_t)(b * 192 + n0 + n) << 12) + px0 + m4 * 4] = val;
    }
}

extern "C" void kernel_launch(void* const* d_in, const int* in_sizes, int n_in,
                              void* d_out, int out_size, void* d_ws, size_t ws_size,
                              hipStream_t stream) {
    const float* x    = (const float*)d_in[0];
    const float* W1   = (const float*)d_in[1];
    const float* b1   = (const float*)d_in[2];
    const float* W2   = (const float*)d_in[3];
    const float* b2   = (const float*)d_in[4];
    const float* temp = (const float*)d_in[5];
    const float* rpb  = (const float*)d_in[6];
    const float* Wp   = (const float*)d_in[7];
    const float* bp   = (const float*)d_in[8];
    float* out = (float*)d_out;

    char* ws = (char*)d_ws;
    unsigned short* Wb1   = (unsigned short*)(ws);
    unsigned short* Wbp   = (unsigned short*)(ws + 221184);
    unsigned short* xT    = (unsigned short*)(ws + 294912);
    unsigned short* qkv1b = (unsigned short*)(ws + 3440640);
    unsigned short* qkv2b = (unsigned short*)(ws + 12877824);
    unsigned short* attnO = (unsigned short*)(ws + 22315008);

    k_cvt <<<dim3(576), 256, 0, stream>>>(W1, Wp, Wb1, Wbp);
    k_xt  <<<dim3(64, 2), 256, 0, stream>>>(x, xT);
    k_gq  <<<dim3(128, 9), 256, 0, stream>>>(xT, Wb1, b1, qkv1b);
    k_dw  <<<dim3(64, 36), 256, 0, stream>>>(qkv1b, W2, b2, qkv2b);
    k_attn<<<dim3(64, 6, 2), 256, 0, stream>>>(qkv2b, temp, rpb, attnO);
    k_gp  <<<dim3(128, 3), 256, 0, stream>>>(attnO, Wbp, bp, out);
}

// Round 5
// 114.814 us; speedup vs baseline: 1.7125x; 1.0206x over previous
//
#include <hip/hip_runtime.h>
#include <math.h>

#define HW 4096

typedef __attribute__((ext_vector_type(8))) short short8;
typedef __attribute__((ext_vector_type(8))) _Float16 half8;
typedef __attribute__((ext_vector_type(4))) float floatx4;

// ---- bf16 helpers (round-to-nearest-even) ----
__device__ inline float bflo(unsigned u) { return __uint_as_float(u << 16); }
__device__ inline float bfhi(unsigned u) { return __uint_as_float(u & 0xffff0000u); }
__device__ inline unsigned short f2bf(float x) {
    unsigned u = __float_as_uint(x);
    return (unsigned short)((u + 0x7fffu + ((u >> 16) & 1u)) >> 16);
}
__device__ inline unsigned f2bf2(float lo, float hi) {
    unsigned a = __float_as_uint(lo), b = __float_as_uint(hi);
    a = (a + 0x7fffu + ((a >> 16) & 1u)) >> 16;
    b = (b + 0x7fffu + ((b >> 16) & 1u)) & 0xffff0000u;
    return a | b;
}
__device__ inline unsigned short f2h(float x) {
    _Float16 h = (_Float16)x;
    return __builtin_bit_cast(unsigned short, h);
}

// ws layout (bytes):
//   Wb1   @ 0        : 576*192*2   = 221184   bf16 [oc][c]
//   Wbp   @ 221184   : 192*192*2   = 73728    bf16 [oc][c]
//   xT    @ 294912   : 2*4096*192*2 = 3145728 bf16 [b*px][c]
//   qkv1b @ 3440640  : 2*18*4096*32*2 = 9437184  bf16 [b][g][px][32]
//   qkv2b @ 12877824 : 9437184                  (after depthwise)
//   attnO @ 22315008 : 2*4096*192*2 = 3145728 bf16 [b*px][c]

// ---------------------------------------------------------------------------
// K0: convert W1 / Wp to bf16 (already [oc][c] = MFMA operand layout).
// ---------------------------------------------------------------------------
__global__ __launch_bounds__(256) void k_cvt(const float* __restrict__ W1,
    const float* __restrict__ Wp, unsigned short* __restrict__ Wb1,
    unsigned short* __restrict__ Wbp)
{
    int idx = blockIdx.x * 256 + threadIdx.x;
    if (idx < 110592) Wb1[idx] = f2bf(W1[idx]);
    else if (idx < 147456) Wbp[idx - 110592] = f2bf(Wp[idx - 110592]);
}

// ---------------------------------------------------------------------------
// K1: transpose+convert x: fp32 [b][c][px] -> bf16 [b*px][c].
// Classic padded-LDS transpose: 64px x 64c fp32 tile, stride 65 ->
// conflict-free on both sides; coalesced global on both sides.
// ---------------------------------------------------------------------------
__global__ __launch_bounds__(256) void k_xt(const float* __restrict__ x,
    unsigned short* __restrict__ xT)
{
    __shared__ float smf[64 * 65];
    const int t = threadIdx.x;
    const int px0 = blockIdx.x << 6;
    const int c0 = blockIdx.y << 6;
    const int b = blockIdx.z;
    const float* xb = x + ((size_t)(b * 192 + c0) << 12) + px0;
    const int pxl = t & 63, csub = t >> 6;
    #pragma unroll
    for (int pass = 0; pass < 16; ++pass) {
        int c = pass * 4 + csub;
        smf[pxl * 65 + c] = xb[((size_t)c << 12) + pxl];
    }
    __syncthreads();
    const int c2 = t & 31, psub = t >> 5;
    unsigned* ob = (unsigned*)xT;
    #pragma unroll
    for (int pass = 0; pass < 8; ++pass) {
        int px = pass * 8 + psub;
        unsigned v = f2bf2(smf[px * 65 + c2 * 2], smf[px * 65 + c2 * 2 + 1]);
        ob[((size_t)((b << 12) + px0 + px)) * 96 + (c0 >> 1) + c2] = v;
    }
}

// ---------------------------------------------------------------------------
// K2: QKV 1x1 conv as bf16 MFMA GEMM. M=8192(px) N=576(oc) K=192.
// ---------------------------------------------------------------------------
__global__ __launch_bounds__(256) void k_gq(const unsigned short* __restrict__ xT,
    const unsigned short* __restrict__ Wb1, const float* __restrict__ b1,
    unsigned short* __restrict__ qkv)
{
    __shared__ __align__(16) unsigned short As[64 * 200];
    __shared__ __align__(16) unsigned short Bs[64 * 200];
    const int t = threadIdx.x;
    const int m0 = blockIdx.x * 64;
    const int n0 = blockIdx.y * 64;
    #pragma unroll
    for (int pass = 0; pass < 6; ++pass) {
        int idx = pass * 256 + t;
        int m = idx / 24, c16 = idx % 24;
        *(uint4*)&As[m * 200 + c16 * 8] = *(const uint4*)&xT[(size_t)(m0 + m) * 192 + c16 * 8];
        *(uint4*)&Bs[m * 200 + c16 * 8] = *(const uint4*)&Wb1[(size_t)(n0 + m) * 192 + c16 * 8];
    }
    __syncthreads();
    const int w = t >> 6, lane = t & 63;
    const int lm = lane & 15, lq = lane >> 4;
    floatx4 acc[4] = {};
    #pragma unroll
    for (int ks = 0; ks < 6; ++ks) {
        short8 bf = *(const short8*)&Bs[(w * 16 + lm) * 200 + ks * 32 + lq * 8];
        #pragma unroll
        for (int mt = 0; mt < 4; ++mt) {
            short8 af = *(const short8*)&As[(mt * 16 + lm) * 200 + ks * 32 + lq * 8];
            acc[mt] = __builtin_amdgcn_mfma_f32_16x16x32_bf16(af, bf, acc[mt], 0, 0, 0);
        }
    }
    __syncthreads();
    const float bias = b1[n0 + w * 16 + lm];
    #pragma unroll
    for (int mt = 0; mt < 4; ++mt)
        #pragma unroll
        for (int r = 0; r < 4; ++r)
            As[(mt * 16 + lq * 4 + r) * 72 + w * 16 + lm] = f2bf(acc[mt][r] + bias);
    __syncthreads();
    #pragma unroll
    for (int pass = 0; pass < 2; ++pass) {
        int idx = pass * 256 + t;           // 64 m x 8 n-groups
        int m = idx >> 3, n8 = idx & 7;
        uint4 val = *(const uint4*)&As[m * 72 + n8 * 8];
        int mg = m0 + m;
        int b = mg >> 12, px = mg & 4095;
        int oc = n0 + n8 * 8;
        int g = oc >> 5, d = oc & 31;
        *(uint4*)&qkv[((((size_t)(b * 18 + g) << 12) + px) << 5) + d] = val;
    }
}

// ---------------------------------------------------------------------------
// K3: depthwise 3x3, bf16 in/out, fp32 math, weights staged in LDS.
// ---------------------------------------------------------------------------
__global__ __launch_bounds__(256) void k_dw(const unsigned short* __restrict__ in,
    const float* __restrict__ W2, const float* __restrict__ b2,
    unsigned short* __restrict__ outq)
{
    __shared__ float wsm[288];
    __shared__ float bsm[32];
    const int t = threadIdx.x;
    const int bg = blockIdx.y;
    const int g = (bg >= 18) ? bg - 18 : bg;
    const int cbase = (g / 6) * 192 + (g % 6) * 32;
    for (int idx = t; idx < 288; idx += 256)
        wsm[idx] = W2[(cbase + (idx & 31)) * 9 + (idx >> 5)];
    if (t < 32) bsm[t] = b2[cbase + t];
    __syncthreads();
    const int px = (blockIdx.x << 6) + (t >> 2);
    const int d8 = t & 3;
    const int i = px >> 6, j = px & 63;
    const unsigned short* base = in + ((size_t)bg << 17);
    float acc[8];
    #pragma unroll
    for (int e = 0; e < 8; ++e) acc[e] = bsm[d8 * 8 + e];
    #pragma unroll
    for (int di = -1; di <= 1; ++di) {
        int ii = i + di;
        if (ii < 0 || ii > 63) continue;
        #pragma unroll
        for (int dj = -1; dj <= 1; ++dj) {
            int jj = j + dj;
            if (jj < 0 || jj > 63) continue;
            int tap = (di + 1) * 3 + dj + 1;
            uint4 u = *(const uint4*)(base + ((((ii << 6) + jj) << 5) + d8 * 8));
            const float* wt = &wsm[tap * 32 + d8 * 8];
            acc[0] = fmaf(bflo(u.x), wt[0], acc[0]);
            acc[1] = fmaf(bfhi(u.x), wt[1], acc[1]);
            acc[2] = fmaf(bflo(u.y), wt[2], acc[2]);
            acc[3] = fmaf(bfhi(u.y), wt[3], acc[3]);
            acc[4] = fmaf(bflo(u.z), wt[4], acc[4]);
            acc[5] = fmaf(bfhi(u.z), wt[5], acc[5]);
            acc[6] = fmaf(bflo(u.w), wt[6], acc[6]);
            acc[7] = fmaf(bfhi(u.w), wt[7], acc[7]);
        }
    }
    uint4 o;
    o.x = f2bf2(acc[0], acc[1]); o.y = f2bf2(acc[2], acc[3]);
    o.z = f2bf2(acc[4], acc[5]); o.w = f2bf2(acc[6], acc[7]);
    *(uint4*)(outq + ((size_t)bg << 17) + ((size_t)px << 5) + d8 * 8) = o;
}

// ---------------------------------------------------------------------------
// K4: MFMA neighborhood attention. Block 256 = (b, head, 8x8 tile), 4 waves.
// S^T[nbr][px] = K-hat x q-hat^T via mfma bf16 (wave w owns px n-tile w,
// q-frag in regs). Mask to -1e30 outside 49-window + rpb bias, softmax over
// padded 208 nbrs (exact). P packed f16 -> LDS (b64 writes, aliases Ks).
// PV = P x V^T via mfma f16. out bf16 [b*px][c].
// LDS: union{Ks[208][40]bf16 | Ps[64][232]f16} + Vts[32][232]f16 + rpb.
// ---------------------------------------------------------------------------
__global__ __launch_bounds__(256) void k_attn(const unsigned short* __restrict__ qkv,
    const float* __restrict__ temp, const float* __restrict__ rpb,
    unsigned short* __restrict__ attnO)
{
    __shared__ __align__(16) char lds[45224];
    unsigned short* Ks  = (unsigned short*)lds;            // [208][40] bf16
    unsigned short* Ps  = (unsigned short*)lds;            // [64][232] f16 (alias)
    unsigned short* Vts = (unsigned short*)(lds + 29696);  // [32][232] f16
    float* rpbs = (float*)(lds + 44544);                   // [169]

    const int t = threadIdx.x;
    const int ti = blockIdx.x >> 3, tj = blockIdx.x & 7;
    const int head = blockIdx.y, b = blockIdx.z;
    const int i0 = ti * 8, j0 = tj * 8;
    const int r0 = min(max(i0 - 3, 0), 50), c0 = min(max(j0 - 3, 0), 50);
    const unsigned short* qpl = qkv + ((size_t)(b * 18 + head) << 17);
    const unsigned short* kpl = qkv + ((size_t)(b * 18 + 6 + head) << 17);
    const unsigned short* vpl = qkv + ((size_t)(b * 18 + 12 + head) << 17);

    // ---- stage K-hat (bf16, l2-normalized) and V^T (f16) ----
    if (t < 196) {
        int r = (t * 2341) >> 15, cc = t - r * 14;
        int pix = ((r0 + r) << 6) + (c0 + cc);
        const uint4* kg = (const uint4*)(kpl + (pix << 5));
        const uint4* vg = (const uint4*)(vpl + (pix << 5));
        float kf[32];
        float ss = 0.f;
        #pragma unroll
        for (int q = 0; q < 4; ++q) {
            uint4 ku = kg[q];
            unsigned uu[4] = {ku.x, ku.y, ku.z, ku.w};
            #pragma unroll
            for (int e = 0; e < 4; ++e) {
                float lo = bflo(uu[e]), hi = bfhi(uu[e]);
                kf[q * 8 + e * 2] = lo; kf[q * 8 + e * 2 + 1] = hi;
                ss = fmaf(lo, lo, fmaf(hi, hi, ss));
            }
        }
        float rinv = 1.0f / fmaxf(sqrtf(ss), 1e-12f);
        #pragma unroll
        for (int q = 0; q < 4; ++q) {
            uint4 p;
            p.x = f2bf2(kf[q * 8 + 0] * rinv, kf[q * 8 + 1] * rinv);
            p.y = f2bf2(kf[q * 8 + 2] * rinv, kf[q * 8 + 3] * rinv);
            p.z = f2bf2(kf[q * 8 + 4] * rinv, kf[q * 8 + 5] * rinv);
            p.w = f2bf2(kf[q * 8 + 6] * rinv, kf[q * 8 + 7] * rinv);
            *(uint4*)&Ks[t * 40 + q * 8] = p;
        }
        #pragma unroll
        for (int q = 0; q < 4; ++q) {
            uint4 vu = vg[q];
            unsigned uu[4] = {vu.x, vu.y, vu.z, vu.w};
            #pragma unroll
            for (int e = 0; e < 4; ++e) {
                Vts[(q * 8 + e * 2) * 232 + t]     = f2h(bflo(uu[e]));
                Vts[(q * 8 + e * 2 + 1) * 232 + t] = f2h(bfhi(uu[e]));
            }
        }
    }
    // zero V^T cols 196..223 (PV pad region must be 0, not garbage)
    for (int idx = t; idx < 448; idx += 256) {
        int row = (idx * 2341) >> 15;       // idx/14
        int c = idx - row * 14;
        ((unsigned*)(Vts + row * 232))[98 + c] = 0u;
    }
    if (t < 169) rpbs[t] = rpb[head * 169 + t];

    // ---- q-hat fragment in registers ----
    const int w = t >> 6, lane = t & 63;
    const int lm = lane & 15, lq = lane >> 4;
    const int px = w * 16 + lm;                 // this lane's pixel (S^T col)
    const int i = i0 + (px >> 3), j = j0 + (px & 7);
    uint4 qu = *(const uint4*)(qpl + ((((i << 6) + j) << 5) + lq * 8));
    float qf[8];
    qf[0] = bflo(qu.x); qf[1] = bfhi(qu.x);
    qf[2] = bflo(qu.y); qf[3] = bfhi(qu.y);
    qf[4] = bflo(qu.z); qf[5] = bfhi(qu.z);
    qf[6] = bflo(qu.w); qf[7] = bfhi(qu.w);
    float qs = 0.f;
    #pragma unroll
    for (int e = 0; e < 8; ++e) qs = fmaf(qf[e], qf[e], qs);
    qs += __shfl_xor(qs, 16);
    qs += __shfl_xor(qs, 32);
    float qinv = 1.0f / fmaxf(sqrtf(qs), 1e-12f);
    short8 bq;
    #pragma unroll
    for (int e = 0; e < 8; ++e) bq[e] = (short)f2bf(qf[e] * qinv);
    __syncthreads();

    // ---- QK^T: S^T[nbr][px], 13 n-tiles of 16 nbrs ----
    floatx4 acc[13];
    #pragma unroll
    for (int mt = 0; mt < 13; ++mt) {
        short8 ak = *(const short8*)&Ks[(mt * 16 + lm) * 40 + lq * 8];
        floatx4 z = {0.f, 0.f, 0.f, 0.f};
        acc[mt] = __builtin_amdgcn_mfma_f32_16x16x32_bf16(ak, bq, z, 0, 0, 0);
    }
    __syncthreads();                        // Ks dead; Ps may overwrite

    // ---- mask + bias + softmax (lane owns px; 52 nbr scores) ----
    const int si = min(max(i - 3, 0), 57), sj = min(max(j - 3, 0), 57);
    const int vloi = si - r0, vloj = sj - c0;
    const int oi = r0 - i + 6, oj = c0 - j + 6;
    const float th = temp[head];
    float mx = -1e30f;
    #pragma unroll
    for (int mt = 0; mt < 13; ++mt) {
        int nb0 = mt * 16 + lq * 4;
        int rh0 = (nb0 * 2341) >> 15;
        int ch0 = nb0 - rh0 * 14;
        #pragma unroll
        for (int r = 0; r < 4; ++r) {
            int ch = ch0 + r, rh = rh0;
            if (ch >= 14) { ch -= 14; rh += 1; }
            int bidx = (rh + oi) * 13 + (ch + oj);
            float bias = rpbs[max(0, min(168, bidx))];
            bool valid = ((unsigned)(rh - vloi) <= 6u) && ((unsigned)(ch - vloj) <= 6u);
            float s = (acc[mt][r] + bias) * th;
            s = valid ? s : -1e30f;
            acc[mt][r] = s;
            mx = fmaxf(mx, s);
        }
    }
    mx = fmaxf(mx, __shfl_xor(mx, 16));
    mx = fmaxf(mx, __shfl_xor(mx, 32));
    float ssum = 0.f;
    #pragma unroll
    for (int mt = 0; mt < 13; ++mt)
        #pragma unroll
        for (int r = 0; r < 4; ++r) {
            float e = __expf(acc[mt][r] - mx);
            acc[mt][r] = e;
            ssum += e;
        }
    ssum += __shfl_xor(ssum, 16);
    ssum += __shfl_xor(ssum, 32);
    const float rs = 1.0f / ssum;

    // zero own Ps pad cols 208..223 (16 rows x 16 shorts, wave-local)
    if (lane < 32) {
        uint4 z4 = {0u, 0u, 0u, 0u};
        *(uint4*)&Ps[(w * 16 + (lane >> 1)) * 232 + 208 + (lane & 1) * 8] = z4;
    }
    // write P (f16): row px, 4 consecutive nbrs per mt -> b64
    #pragma unroll
    for (int mt = 0; mt < 13; ++mt) {
        unsigned lo = (unsigned)f2h(acc[mt][0] * rs) | ((unsigned)f2h(acc[mt][1] * rs) << 16);
        unsigned hi = (unsigned)f2h(acc[mt][2] * rs) | ((unsigned)f2h(acc[mt][3] * rs) << 16);
        *(uint2*)&Ps[px * 232 + mt * 16 + lq * 4] = make_uint2(lo, hi);
    }
    __syncthreads();                        // all P rows visible

    // ---- PV: O[px][d] = P x V^T, m-tile w, 7 k-steps x 2 n-tiles ----
    floatx4 oacc[2] = {};
    #pragma unroll
    for (int ks = 0; ks < 7; ++ks) {
        half8 ap = *(const half8*)&Ps[(w * 16 + lm) * 232 + ks * 32 + lq * 8];
        #pragma unroll
        for (int n2 = 0; n2 < 2; ++n2) {
            half8 bv = *(const half8*)&Vts[(n2 * 16 + lm) * 232 + ks * 32 + lq * 8];
            oacc[n2] = __builtin_amdgcn_mfma_f32_16x16x32_f16(ap, bv, oacc[n2], 0, 0, 0);
        }
    }
    // epilogue: rows px2 = w*16+lq*4+r, col d = n2*16+lm
    #pragma unroll
    for (int n2 = 0; n2 < 2; ++n2)
        #pragma unroll
        for (int r = 0; r < 4; ++r) {
            int p2 = w * 16 + lq * 4 + r;
            int i2 = i0 + (p2 >> 3), j2 = j0 + (p2 & 7);
            attnO[((size_t)((b << 12) + (i2 << 6) + j2)) * 192 + head * 32 + n2 * 16 + lm]
                = f2bf(oacc[n2][r]);
        }
}

// ---------------------------------------------------------------------------
// K5: proj 1x1 as bf16 MFMA GEMM. M=8192 N=192 K=192. fp32 NCHW out + bias.
// ---------------------------------------------------------------------------
__global__ __launch_bounds__(256) void k_gp(const unsigned short* __restrict__ Ain,
    const unsigned short* __restrict__ Wbp, const float* __restrict__ bp,
    float* __restrict__ out)
{
    __shared__ __align__(16) unsigned short As[64 * 200];
    __shared__ __align__(16) unsigned short Bs[64 * 200];
    const int t = threadIdx.x;
    const int m0 = blockIdx.x * 64;
    const int n0 = blockIdx.y * 64;
    #pragma unroll
    for (int pass = 0; pass < 6; ++pass) {
        int idx = pass * 256 + t;
        int m = idx / 24, c16 = idx % 24;
        *(uint4*)&As[m * 200 + c16 * 8] = *(const uint4*)&Ain[(size_t)(m0 + m) * 192 + c16 * 8];
        *(uint4*)&Bs[m * 200 + c16 * 8] = *(const uint4*)&Wbp[(size_t)(n0 + m) * 192 + c16 * 8];
    }
    __syncthreads();
    const int w = t >> 6, lane = t & 63;
    const int lm = lane & 15, lq = lane >> 4;
    floatx4 acc[4] = {};
    #pragma unroll
    for (int ks = 0; ks < 6; ++ks) {
        short8 bf = *(const short8*)&Bs[(w * 16 + lm) * 200 + ks * 32 + lq * 8];
        #pragma unroll
        for (int mt = 0; mt < 4; ++mt) {
            short8 af = *(const short8*)&As[(mt * 16 + lm) * 200 + ks * 32 + lq * 8];
            acc[mt] = __builtin_amdgcn_mfma_f32_16x16x32_bf16(af, bf, acc[mt], 0, 0, 0);
        }
    }
    __syncthreads();
    float* fs = (float*)As;                 // [n][m] stride 68
    const float bias = bp[n0 + w * 16 + lm];
    #pragma unroll
    for (int mt = 0; mt < 4; ++mt)
        #pragma unroll
        for (int r = 0; r < 4; ++r)
            fs[(w * 16 + lm) * 68 + mt * 16 + lq * 4 + r] = acc[mt][r] + bias;
    __syncthreads();
    const int b = m0 >> 12, px0 = m0 & 4095;
    #pragma unroll
    for (int pass = 0; pass < 4; ++pass) {
        int idx = pass * 256 + t;           // 64 n x 16 m-quads
        int n = idx >> 4, m4 = idx & 15;
        float4 val = *(const float4*)&fs[n * 68 + m4 * 4];
        *(float4*)&out[((size_t)(b * 192 + n0 + n) << 12) + px0 + m4 * 4] = val;
    }
}

extern "C" void kernel_launch(void* const* d_in, const int* in_sizes, int n_in,
                              void* d_out, int out_size, void* d_ws, size_t ws_size,
                              hipStream_t stream) {
    const float* x    = (const float*)d_in[0];
    const float* W1   = (const float*)d_in[1];
    const float* b1   = (const float*)d_in[2];
    const float* W2   = (const float*)d_in[3];
    const float* b2   = (const float*)d_in[4];
    const float* temp = (const float*)d_in[5];
    const float* rpb  = (const float*)d_in[6];
    const float* Wp   = (const float*)d_in[7];
    const float* bp   = (const float*)d_in[8];
    float* out = (float*)d_out;

    char* ws = (char*)d_ws;
    unsigned short* Wb1   = (unsigned short*)(ws);
    unsigned short* Wbp   = (unsigned short*)(ws + 221184);
    unsigned short* xT    = (unsigned short*)(ws + 294912);
    unsigned short* qkv1b = (unsigned short*)(ws + 3440640);
    unsigned short* qkv2b = (unsigned short*)(ws + 12877824);
    unsigned short* attnO = (unsigned short*)(ws + 22315008);

    k_cvt <<<dim3(576), 256, 0, stream>>>(W1, Wp, Wb1, Wbp);
    k_xt  <<<dim3(64, 3, 2), 256, 0, stream>>>(x, xT);
    k_gq  <<<dim3(128, 9), 256, 0, stream>>>(xT, Wb1, b1, qkv1b);
    k_dw  <<<dim3(64, 36), 256, 0, stream>>>(qkv1b, W2, b2, qkv2b);
    k_attn<<<dim3(64, 6, 2), 256, 0, stream>>>(qkv2b, temp, rpb, attnO);
    k_gp  <<<dim3(128, 3), 256, 0, stream>>>(attnO, Wbp, bp, out);
}